// Round 6
// baseline (571.788 us; speedup 1.0000x reference)
//
#include <hip/hip_runtime.h>

typedef long long i64;
typedef unsigned short u16;
typedef __attribute__((ext_vector_type(8))) short short8;
typedef __attribute__((ext_vector_type(4))) float f32x4;

#define Bv 8
#define Nv 1024
#define Dv 768
#define Hh 4
#define DKv 192
#define BND ((i64)Bv * Nv * Dv)      /* 6,291,456  */
#define HBND ((i64)Hh * BND)         /* 25,165,824 */

__device__ __forceinline__ u16 f2bf(float f) {
    unsigned u = __builtin_bit_cast(unsigned, f);
    u += 0x7fffu + ((u >> 16) & 1u);
    return (u16)(u >> 16);
}
__device__ __forceinline__ float bf2f(u16 h) {
    unsigned u = ((unsigned)h) << 16;
    return __builtin_bit_cast(float, u);
}

// async global->LDS, 16B per lane. LDS dest must be wave-uniform base.
__device__ __forceinline__ void gl_lds16(const u16* g, u16* l) {
    __builtin_amdgcn_global_load_lds(
        (const __attribute__((address_space(1))) void*)g,
        (__attribute__((address_space(3))) void*)l, 16, 0, 0);
}

// ---------------------------------------------------------------------------
// bf16 MFMA GEMM:  C[z] = epilogue( A[z] (MxK) @ Bt[z]^T (NxK) + bias[z] )
// 128x128 tile, BK=64, 256 threads (4 waves, 64x64 sub-tile each).
// Swapped mfma operand order (first operand = Bt rows) -> C/D reg dim runs
// along contiguous n -> vector epilogue. XOR slot swizzle both sides.
// 1D launch + XCD-chunked swizzle: L = (bid&7)*(grid/8) + (bid>>3);
// ORD 0: bn = L%NBN, bm = (L/NBN)%NBM, z = L/(NBN*NBM)   (bn fastest, z slow)
// ORD 1: bn = L%NBN, z  = (L/NBN)%NZ,  bm = L/(NBN*NZ)   (bm slowest)
// EPI: 0 = f32 store (+bias), 1 = bf16 store (+bias),
//      2 = X-update: X = bf16( bf2f(X) + relu(acc + bias) )  (u16*, RMW)
// CATK: A is X in (h,BN,768) layout; logical k = h*768 + d (cat view).
// bias2: if non-null, z >= NZ/2 uses bias2[z - NZ/2] (fused q/k dispatch).
// zmaskBt: Bt batch offset uses (z & zmaskBt) (iter-0 shared-H indexing).
// ---------------------------------------------------------------------------
template <int EPI, bool CATK, int ORD, int NBN, int NBM, int NZ>
__global__ __launch_bounds__(256) void gemm_bf16(
    const u16* __restrict__ A, i64 sA, int lda,
    const u16* __restrict__ Bt, i64 sBt, int ldbt, int zmaskBt,
    const float* __restrict__ bias, i64 sBias, const float* __restrict__ bias2,
    void* __restrict__ Cv, i64 sC, int ldc, int K, int koff)
{
    __shared__ u16 Asb[128 * 64];
    __shared__ u16 Bsb[128 * 64];

    const int L = (blockIdx.x & 7) * ((NBN * NBM * NZ) >> 3) + (blockIdx.x >> 3);
    int bn, bm, z;
    if (ORD == 0) {
        bn = L % NBN; const int t2 = L / NBN; bm = t2 % NBM; z = t2 / NBM;
    } else {
        bn = L % NBN; const int t2 = L / NBN; z = t2 % NZ; bm = t2 / NZ;
    }

    A  += (i64)z * sA;
    Bt += (i64)(z & zmaskBt) * sBt;
    const float* bp = bias;
    int zb = z;
    if (bias2 != nullptr && z >= NZ / 2) { bp = bias2; zb = z - NZ / 2; }
    if (bp) bp += (i64)zb * sBias;
    const int kb = z * koff;

    const int bmp = bm * 128, bnp = bn * 128;
    const int tid = threadIdx.x;
    const int w = tid >> 6, l = tid & 63;
    const int wr = w >> 1, wc = w & 1;
    const int kgrp = l >> 4, lr = l & 15;

    const u16* Ab = A + (i64)bmp * lda;
    const u16* Bb = Bt + (i64)bnp * ldbt;

    f32x4 acc[4][4];   // [i: n-frag (reg dim)][j: m-frag (lane dim)]
    #pragma unroll
    for (int i = 0; i < 4; ++i)
        #pragma unroll
        for (int j = 0; j < 4; ++j)
            acc[i][j] = (f32x4){0.f, 0.f, 0.f, 0.f};

    for (int k0i = 0; k0i < K; k0i += 64) {
        const int k0 = kb + k0i;
        if (k0i) __syncthreads();
        #pragma unroll
        for (int t = 0; t < 4; ++t) {
            const int idx = t * 256 + tid;
            const int r = idx >> 3, s = idx & 7;
            const int ss = s ^ (r & 7);
            const u16* src;
            if (CATK) {
                src = A + (i64)(k0 / Dv) * BND + (i64)(bmp + r) * Dv + (k0 % Dv) + ss * 8;
            } else {
                src = Ab + (i64)r * lda + k0 + ss * 8;
            }
            gl_lds16(src, &Asb[(t * 256 + w * 64) * 8]);
        }
        #pragma unroll
        for (int t = 0; t < 4; ++t) {
            const int idx = t * 256 + tid;
            const int r = idx >> 3, s = idx & 7;
            const int ss = s ^ (r & 7);
            gl_lds16(Bb + (i64)r * ldbt + k0 + ss * 8, &Bsb[(t * 256 + w * 64) * 8]);
        }
        __syncthreads();

        #pragma unroll
        for (int ks = 0; ks < 2; ++ks) {
            const int slot = ks * 4 + kgrp;
            short8 a[4], b[4];
            #pragma unroll
            for (int i = 0; i < 4; ++i) {          // Bt rows (n side)
                const int r = wc * 64 + i * 16 + lr;
                a[i] = *(const short8*)&Bsb[r * 64 + ((slot ^ (r & 7)) << 3)];
            }
            #pragma unroll
            for (int j = 0; j < 4; ++j) {          // A rows (m side)
                const int r = wr * 64 + j * 16 + lr;
                b[j] = *(const short8*)&Asb[r * 64 + ((slot ^ (r & 7)) << 3)];
            }
            #pragma unroll
            for (int i = 0; i < 4; ++i)
                #pragma unroll
                for (int j = 0; j < 4; ++j)
                    acc[i][j] = __builtin_amdgcn_mfma_f32_16x16x32_bf16(
                        a[i], b[j], acc[i][j], 0, 0, 0);
        }
    }

    f32x4 bj[4];
    #pragma unroll
    for (int i = 0; i < 4; ++i) {
        const int nb = bnp + wc * 64 + i * 16 + kgrp * 4;
        bj[i] = bp ? *(const f32x4*)&bp[nb] : (f32x4){0.f, 0.f, 0.f, 0.f};
    }

    #pragma unroll
    for (int j = 0; j < 4; ++j) {
        const int m = bmp + wr * 64 + j * 16 + lr;
        #pragma unroll
        for (int i = 0; i < 4; ++i) {
            const int nb = bnp + wc * 64 + i * 16 + kgrp * 4;
            const i64 off = (i64)z * sC + (i64)m * ldc + nb;
            f32x4 v = acc[i][j] + bj[i];
            if (EPI == 0) {
                *(f32x4*)&((float*)Cv)[off] = v;
            } else if (EPI == 1) {
                ushort4 o;
                o.x = f2bf(v[0]); o.y = f2bf(v[1]);
                o.z = f2bf(v[2]); o.w = f2bf(v[3]);
                *(ushort4*)&((u16*)Cv)[off] = o;
            } else {
                u16* xp = (u16*)Cv + off;
                ushort4 old = *(const ushort4*)xp;
                ushort4 o;
                o.x = f2bf(bf2f(old.x) + fmaxf(v[0], 0.f));
                o.y = f2bf(bf2f(old.y) + fmaxf(v[1], 0.f));
                o.z = f2bf(bf2f(old.z) + fmaxf(v[2], 0.f));
                o.w = f2bf(bf2f(old.w) + fmaxf(v[3], 0.f));
                *(ushort4*)xp = o;
            }
        }
    }
}

// ---------------------------------------------------------------------------
// Fused 3-edge masked scores (MFMA), 128n x 64m tile, TRI-buffered staging
// with depth-2 prefetch: stage phase ci+2 while computing ci. Counted
// vmcnt(12) steady state (2 phases x 6 loads in flight), 6/0 at the tail.
// Buffer reuse hazard: buf (ci+2)%3 was last read in phase ci-1, which ends
// with lgkmcnt(0)+barrier before any wave issues this stage. setprio(1)
// around the MFMA cluster (T5: waves now have stage/compute role split).
// 1D launch 4096: b = bid&7 (b-per-XCD), then h fastest, mt, nt (adj reuse).
// ---------------------------------------------------------------------------
__global__ __launch_bounds__(256, 2) void scores_mfma(
    const u16* __restrict__ qb, const u16* __restrict__ kb,
    const int* __restrict__ adj, u16* __restrict__ sb)
{
    __shared__ u16 Qs[3][128 * 64];   // 48 KB
    __shared__ u16 Ks[3][64 * 64];    // 24 KB

    const int bid = blockIdx.x;
    const int b = bid & 7;
    const int t2 = bid >> 3;          // [0,512)
    const int h = t2 & 3;
    const int mt = (t2 >> 2) & 15;
    const int nt = t2 >> 6;           // [0,8)
    const int m0 = mt * 64, n0 = nt * 128;
    const int zga = h * 8 + b;

    const int tid = threadIdx.x;
    const int w = tid >> 6, l = tid & 63;
    const int wn = w >> 1, wm = w & 1;   // wn: n-half (64 rows), wm: m-half (32)
    const int kgrp = l >> 4, lr = l & 15;

    const i64 qoff = ((i64)b * Nv + n0) * Dv + h * DKv;
    const i64 koff = ((i64)b * Nv + m0) * Dv + h * DKv;

#define STAGE_SC(ci_, buf_) { \
    const int e_ = (ci_) / 3, k0_ = ((ci_) % 3) * 64; \
    const u16* qe_ = qb + (i64)e_ * BND + qoff; \
    const u16* ke_ = kb + (i64)e_ * BND + koff; \
    _Pragma("unroll") \
    for (int t = 0; t < 4; ++t) { \
        const int idx2 = t * 256 + tid; \
        const int r = idx2 >> 3, s = idx2 & 7; \
        const int ss = s ^ (r & 7); \
        gl_lds16(qe_ + (i64)r * Dv + k0_ + ss * 8, &Qs[buf_][(t * 256 + w * 64) * 8]); \
    } \
    _Pragma("unroll") \
    for (int t = 0; t < 2; ++t) { \
        const int idx2 = t * 256 + tid; \
        const int r = idx2 >> 3, s = idx2 & 7; \
        const int ss = s ^ (r & 7); \
        gl_lds16(ke_ + (i64)r * Dv + k0_ + ss * 8, &Ks[buf_][(t * 256 + w * 64) * 8]); \
    } }

    f32x4 acc[3][2][4];   // [edge][m-frag (reg dim)][n-frag (lane dim)]
    #pragma unroll
    for (int e = 0; e < 3; ++e)
        #pragma unroll
        for (int i = 0; i < 2; ++i)
            #pragma unroll
            for (int j = 0; j < 4; ++j)
                acc[e][i][j] = (f32x4){0.f, 0.f, 0.f, 0.f};

    STAGE_SC(0, 0)
    STAGE_SC(1, 1)

    #pragma unroll
    for (int ci = 0; ci < 9; ++ci) {
        const int cur = ci % 3;
        if (ci < 7) {
            const int nxt = (ci + 2) % 3;
            STAGE_SC(ci + 2, nxt)
            asm volatile("s_waitcnt vmcnt(12)" ::: "memory");
        } else if (ci == 7) {
            asm volatile("s_waitcnt vmcnt(6)" ::: "memory");
        } else {
            asm volatile("s_waitcnt vmcnt(0)" ::: "memory");
        }
        __builtin_amdgcn_s_barrier();
        asm volatile("" ::: "memory");

        const int e = ci / 3;
        __builtin_amdgcn_s_setprio(1);
        #pragma unroll
        for (int ks = 0; ks < 2; ++ks) {
            const int slot = ks * 4 + kgrp;
            short8 a[2], bq2[4];
            #pragma unroll
            for (int i = 0; i < 2; ++i) {          // K rows (m side, reg dim)
                const int r = wm * 32 + i * 16 + lr;
                a[i] = *(const short8*)&Ks[cur][r * 64 + ((slot ^ (r & 7)) << 3)];
            }
            #pragma unroll
            for (int j = 0; j < 4; ++j) {          // Q rows (n side, lane dim)
                const int r = wn * 64 + j * 16 + lr;
                bq2[j] = *(const short8*)&Qs[cur][r * 64 + ((slot ^ (r & 7)) << 3)];
            }
            #pragma unroll
            for (int i = 0; i < 2; ++i)
                #pragma unroll
                for (int j = 0; j < 4; ++j)
                    acc[e][i][j] = __builtin_amdgcn_mfma_f32_16x16x32_bf16(
                        a[i], bq2[j], acc[e][i][j], 0, 0, 0);
        }
        __builtin_amdgcn_s_setprio(0);

        asm volatile("s_waitcnt lgkmcnt(0)" ::: "memory");
        __builtin_amdgcn_s_barrier();
    }
#undef STAGE_SC

    const float scale = 0.07216878364870323f;  // 1/sqrt(192)
    #pragma unroll
    for (int i = 0; i < 2; ++i) {
        const int mb = m0 + wm * 32 + i * 16 + kgrp * 4;
        #pragma unroll
        for (int j = 0; j < 4; ++j) {
            const int n = n0 + wn * 64 + j * 16 + lr;
            const int4 adjv = *(const int4*)&adj[((i64)b * Nv + n) * Nv + mb];
            const int av[4] = {adjv.x, adjv.y, adjv.z, adjv.w};
            ushort4 o;
            #pragma unroll
            for (int rg = 0; rg < 4; ++rg) {
                float f = 0.f;
                if (av[rg] == 1) f = acc[0][i][j][rg];
                else if (av[rg] == 2) f = acc[1][i][j][rg];
                else if (av[rg] == 3) f = acc[2][i][j][rg];
                f *= scale;
                if (f == 0.f) f = -1e9f;
                ((u16*)&o)[rg] = f2bf(f);
            }
            *(ushort4*)&sb[((i64)zga * Nv + n) * Nv + mb] = o;
        }
    }
}

// row softmax over 1024 cols: read S bf16, write ga f32 (output) + P bf16
__global__ __launch_bounds__(256) void softmax_k(const u16* __restrict__ sb,
                                                 float* __restrict__ ga,
                                                 u16* __restrict__ gab)
{
    const i64 row = blockIdx.x;
    const int tid = threadIdx.x;
    const int wid = tid >> 6, lane = tid & 63;

    ushort4 sv = *(const ushort4*)&sb[row * (i64)Nv + tid * 4];
    float4 v;
    v.x = bf2f(sv.x); v.y = bf2f(sv.y); v.z = bf2f(sv.z); v.w = bf2f(sv.w);

    float m = fmaxf(fmaxf(v.x, v.y), fmaxf(v.z, v.w));
    #pragma unroll
    for (int o = 32; o >= 1; o >>= 1) m = fmaxf(m, __shfl_xor(m, o));

    __shared__ float red[4];
    if (lane == 0) red[wid] = m;
    __syncthreads();
    m = fmaxf(fmaxf(red[0], red[1]), fmaxf(red[2], red[3]));

    float e0 = expf(v.x - m), e1 = expf(v.y - m), e2 = expf(v.z - m), e3 = expf(v.w - m);
    float s = e0 + e1 + e2 + e3;
    #pragma unroll
    for (int o = 32; o >= 1; o >>= 1) s += __shfl_xor(s, o);
    __syncthreads();
    if (lane == 0) red[wid] = s;
    __syncthreads();
    s = red[0] + red[1] + red[2] + red[3];

    const float inv = 1.0f / s;
    float4 o;
    o.x = e0 * inv; o.y = e1 * inv; o.z = e2 * inv; o.w = e3 * inv;
    *(float4*)&ga[row * (i64)Nv + tid * 4] = o;

    ushort4 ob;
    ob.x = f2bf(o.x); ob.y = f2bf(o.y); ob.z = f2bf(o.z); ob.w = f2bf(o.w);
    *(ushort4*)&gab[row * (i64)Nv + tid * 4] = ob;
}

// nodes f32 -> nodesb bf16 + X broadcast x4 (one read, five writes)
__global__ __launch_bounds__(256) void prep_k(const float* __restrict__ nodes,
                                              u16* __restrict__ nodesb,
                                              u16* __restrict__ Xb)
{
    const i64 i = (i64)blockIdx.x * 256 + threadIdx.x;  // over BND/4
    float4 v = ((const float4*)nodes)[i];
    ushort4 o;
    o.x = f2bf(v.x); o.y = f2bf(v.y); o.z = f2bf(v.z); o.w = f2bf(v.w);
    ((ushort4*)nodesb)[i] = o;
    const i64 q4 = BND / 4;
    #pragma unroll
    for (int h = 0; h < Hh; ++h) ((ushort4*)Xb)[(i64)h * q4 + i] = o;
}

// all weight transposes in one dispatch. z<3: Wq[e]; 3..5: Wk[e]; 6,7: gcnW;
// 8..11: Wagg 768-row slice. All 768x768 transposes.
__global__ __launch_bounds__(256) void trans_all(
    const float* __restrict__ Wq, const float* __restrict__ Wk,
    const float* __restrict__ gcnW, const float* __restrict__ Wagg,
    u16* __restrict__ wqkt, u16* __restrict__ gcnWt, u16* __restrict__ waggt)
{
    const int z = blockIdx.z;
    const i64 W768 = (i64)768 * 768;
    const float* src;
    u16* dst;
    int ldo;
    if (z < 3)      { src = Wq + z * W768;        dst = wqkt + z * W768;          ldo = 768; }
    else if (z < 6) { src = Wk + (z - 3) * W768;  dst = wqkt + (i64)z * W768;     ldo = 768; }
    else if (z < 8) { src = gcnW + (z - 6) * W768; dst = gcnWt + (i64)(z - 6) * W768; ldo = 768; }
    else            { src = Wagg + (i64)(z - 8) * W768; dst = waggt + (i64)(z - 8) * 768; ldo = 3072; }

    __shared__ u16 t[32][33];
    const int c0 = blockIdx.x * 32, r0 = blockIdx.y * 32;
    const int tx = threadIdx.x & 31, ty = threadIdx.x >> 5;
    #pragma unroll
    for (int i = ty; i < 32; i += 8)
        t[i][tx] = f2bf(src[(i64)(r0 + i) * 768 + c0 + tx]);
    __syncthreads();
    #pragma unroll
    for (int i = ty; i < 32; i += 8)
        dst[(i64)(c0 + i) * ldo + r0 + tx] = t[tx][i];
}

// out = p0 + p1 + bias (split-K reduce), float4 per thread
__global__ __launch_bounds__(256) void addbias_k(
    const float* __restrict__ p0, const float* __restrict__ p1,
    const float* __restrict__ bias, float* __restrict__ out)
{
    const i64 i4 = (i64)blockIdx.x * 256 + threadIdx.x;  // over BND/4
    const int nb = (int)((i4 * 4) % Dv);
    float4 a = ((const float4*)p0)[i4];
    float4 b = ((const float4*)p1)[i4];
    float4 bv = *(const float4*)&bias[nb];
    float4 o;
    o.x = a.x + b.x + bv.x; o.y = a.y + b.y + bv.y;
    o.z = a.z + b.z + bv.z; o.w = a.w + b.w + bv.w;
    ((float4*)out)[i4] = o;
}

// ---------------------------------------------------------------------------
extern "C" void kernel_launch(void* const* d_in, const int* in_sizes, int n_in,
                              void* d_out, int out_size, void* d_ws, size_t ws_size,
                              hipStream_t stream)
{
    const float* nodes = (const float*)d_in[0];
    const int*   adj   = (const int*)d_in[1];
    const float* Wq    = (const float*)d_in[2];
    const float* bq    = (const float*)d_in[3];
    const float* Wk    = (const float*)d_in[4];
    const float* bk    = (const float*)d_in[5];
    const float* gcnW  = (const float*)d_in[6];
    const float* gcnb  = (const float*)d_in[7];
    const float* Wagg  = (const float*)d_in[8];
    const float* bagg  = (const float*)d_in[9];

    float* out = (float*)d_out;             // (B,N,D) f32
    float* gaf = out + BND;                 // (H,B,N,N) f32

    const i64 W768 = (i64)768 * 768;
    u16* ws     = (u16*)d_ws;
    u16* qb     = ws;                       // 3*BND           (phase 1)
    u16* kb2    = ws + 3 * BND;             // 3*BND           (phase 1)
    u16* gab    = ws;                       // HBND bf16       (alias after scores)
    u16* nodesb = ws + 6 * BND;             // BND
    u16* gcnWt  = nodesb + BND;             // 2*W768
    u16* waggt  = gcnWt + 2 * W768;         // 4*W768
    u16* Xb     = waggt + 4 * W768;         // HBND
    u16* Htb    = Xb + HBND;                // HBND region, time-shared:
    u16* wqkt   = Htb;                      //   6*W768 (dead after q/k proj)
    u16* sbuf   = Htb;                      //   HBND (S bf16; dead after softmax)
    float* part = (float*)Htb;              //   2*BND f32 (final split-K)

    dim3 blk(256);

    prep_k<<<dim3((unsigned)(BND / 4 / 256)), blk, 0, stream>>>(nodes, nodesb, Xb);
    trans_all<<<dim3(24, 24, 12), blk, 0, stream>>>(Wq, Wk, gcnW, Wagg, wqkt, gcnWt, waggt);

    // fused q/k projections: z 0..2 -> q (bias bq), z 3..5 -> k (bias bk)
    gemm_bf16<1, false, 1, 6, 64, 6><<<dim3(2304), blk, 0, stream>>>(
        nodesb, 0, Dv, wqkt, W768, Dv, -1, bq, Dv, bk, qb, BND, Dv, Dv, 0);

    // fused masked scores -> S bf16 scratch (128n x 64m tiles, tri-buffered)
    scores_mfma<<<dim3(4096), blk, 0, stream>>>(qb, kb2, adj, sbuf);

    // softmax: ga f32 (output) + P bf16 (gab aliases q/k, both dead now)
    softmax_k<<<dim3(Hh * Bv * Nv), blk, 0, stream>>>(sbuf, gaf, gab);

    for (int it = 0; it < 2; ++it) {
        if (it == 0) {
            // iter 0: X identical across heads -> H0^T = gcnW[0]^T @ nodes^T
            // (768 x 8192 only), Xupd indexes it by b = z&7.
            gemm_bf16<1, false, 0, 64, 6, 1><<<dim3(384), blk, 0, stream>>>(
                gcnWt, 0, Dv, nodesb, 0, Dv, -1, nullptr, 0, nullptr,
                Htb, 0, 8192, Dv, 0);
            gemm_bf16<2, false, 0, 6, 8, 32><<<dim3(1536), blk, 0, stream>>>(
                gab, (i64)Nv * Nv, Nv, Htb, 1024, 8192, 7, gcnb, 0, nullptr,
                Xb, (i64)Nv * Dv, Dv, Nv, 0);
        } else {
            // iter 1: full H^T = gcnW[1]^T @ X^T (768 x 32768)
            gemm_bf16<1, false, 0, 256, 6, 1><<<dim3(1536), blk, 0, stream>>>(
                gcnWt + W768, 0, Dv, Xb, 0, Dv, -1, nullptr, 0, nullptr,
                Htb, 0, 32768, Dv, 0);
            gemm_bf16<2, false, 0, 6, 8, 32><<<dim3(1536), blk, 0, stream>>>(
                gab, (i64)Nv * Nv, Nv, Htb, 1024, 32768, -1, gcnb + (i64)Dv, 0, nullptr,
                Xb, (i64)Nv * Dv, Dv, Nv, 0);
        }
    }

    // final: out = cat(X) @ W_agg + b_agg, split-K x2 into f32 partials
    gemm_bf16<0, true, 0, 6, 64, 2><<<dim3(768), blk, 0, stream>>>(
        Xb, 0, Dv, waggt, 0, Hh * Dv, -1, nullptr, 0, nullptr,
        part, BND, Dv, (Hh * Dv) / 2, (Hh * Dv) / 2);

    addbias_k<<<dim3((unsigned)(BND / 4 / 256)), blk, 0, stream>>>(
        part, part + BND, bagg, out);
}

// Round 7
// 542.275 us; speedup vs baseline: 1.0544x; 1.0544x over previous
//
#include <hip/hip_runtime.h>

typedef long long i64;
typedef unsigned short u16;
typedef __attribute__((ext_vector_type(8))) short short8;
typedef __attribute__((ext_vector_type(4))) float f32x4;

#define Bv 8
#define Nv 1024
#define Dv 768
#define Hh 4
#define DKv 192
#define BND ((i64)Bv * Nv * Dv)      /* 6,291,456  */
#define HBND ((i64)Hh * BND)         /* 25,165,824 */

__device__ __forceinline__ u16 f2bf(float f) {
    unsigned u = __builtin_bit_cast(unsigned, f);
    u += 0x7fffu + ((u >> 16) & 1u);
    return (u16)(u >> 16);
}
__device__ __forceinline__ float bf2f(u16 h) {
    unsigned u = ((unsigned)h) << 16;
    return __builtin_bit_cast(float, u);
}

// async global->LDS, 16B per lane. LDS dest must be wave-uniform base.
__device__ __forceinline__ void gl_lds16(const u16* g, u16* l) {
    __builtin_amdgcn_global_load_lds(
        (const __attribute__((address_space(1))) void*)g,
        (__attribute__((address_space(3))) void*)l, 16, 0, 0);
}

// ---------------------------------------------------------------------------
// bf16 MFMA GEMM:  C[z] = epilogue( A[z] (MxK) @ Bt[z]^T (NxK) + bias[z] )
// 128x128 tile, BK=64, 256 threads (4 waves, 64x64 sub-tile each).
// Swapped mfma operand order (first operand = Bt rows) -> C/D reg dim runs
// along contiguous n -> vector epilogue. XOR slot swizzle both sides.
// 1D launch + XCD-chunked swizzle: L = (bid&7)*(grid/8) + (bid>>3);
// ORD 0: bn = L%NBN, bm = (L/NBN)%NBM, z = L/(NBN*NBM)   (bn fastest, z slow)
// ORD 1: bn = L%NBN, z  = (L/NBN)%NZ,  bm = L/(NBN*NZ)   (bm slowest)
// EPI: 0 = f32 store (+bias), 1 = bf16 store (+bias),
//      2 = X-update: X = bf16( bf2f(X) + relu(acc + bias) )  (u16*, RMW)
// CATK: A is X in (h,BN,768) layout; logical k = h*768 + d (cat view).
// bias2: if non-null, z >= NZ/2 uses bias2[z - NZ/2] (fused q/k dispatch).
// zmaskBt: Bt batch offset uses (z & zmaskBt) (shared-Bt indexing).
// ---------------------------------------------------------------------------
template <int EPI, bool CATK, int ORD, int NBN, int NBM, int NZ>
__global__ __launch_bounds__(256) void gemm_bf16(
    const u16* __restrict__ A, i64 sA, int lda,
    const u16* __restrict__ Bt, i64 sBt, int ldbt, int zmaskBt,
    const float* __restrict__ bias, i64 sBias, const float* __restrict__ bias2,
    void* __restrict__ Cv, i64 sC, int ldc, int K, int koff)
{
    __shared__ u16 Asb[128 * 64];
    __shared__ u16 Bsb[128 * 64];

    const int L = (blockIdx.x & 7) * ((NBN * NBM * NZ) >> 3) + (blockIdx.x >> 3);
    int bn, bm, z;
    if (ORD == 0) {
        bn = L % NBN; const int t2 = L / NBN; bm = t2 % NBM; z = t2 / NBM;
    } else {
        bn = L % NBN; const int t2 = L / NBN; z = t2 % NZ; bm = t2 / NZ;
    }

    A  += (i64)z * sA;
    Bt += (i64)(z & zmaskBt) * sBt;
    const float* bp = bias;
    int zb = z;
    if (bias2 != nullptr && z >= NZ / 2) { bp = bias2; zb = z - NZ / 2; }
    if (bp) bp += (i64)zb * sBias;
    const int kb = z * koff;

    const int bmp = bm * 128, bnp = bn * 128;
    const int tid = threadIdx.x;
    const int w = tid >> 6, l = tid & 63;
    const int wr = w >> 1, wc = w & 1;
    const int kgrp = l >> 4, lr = l & 15;

    const u16* Ab = A + (i64)bmp * lda;
    const u16* Bb = Bt + (i64)bnp * ldbt;

    f32x4 acc[4][4];   // [i: n-frag (reg dim)][j: m-frag (lane dim)]
    #pragma unroll
    for (int i = 0; i < 4; ++i)
        #pragma unroll
        for (int j = 0; j < 4; ++j)
            acc[i][j] = (f32x4){0.f, 0.f, 0.f, 0.f};

    for (int k0i = 0; k0i < K; k0i += 64) {
        const int k0 = kb + k0i;
        if (k0i) __syncthreads();
        #pragma unroll
        for (int t = 0; t < 4; ++t) {
            const int idx = t * 256 + tid;
            const int r = idx >> 3, s = idx & 7;
            const int ss = s ^ (r & 7);
            const u16* src;
            if (CATK) {
                src = A + (i64)(k0 / Dv) * BND + (i64)(bmp + r) * Dv + (k0 % Dv) + ss * 8;
            } else {
                src = Ab + (i64)r * lda + k0 + ss * 8;
            }
            gl_lds16(src, &Asb[(t * 256 + w * 64) * 8]);
        }
        #pragma unroll
        for (int t = 0; t < 4; ++t) {
            const int idx = t * 256 + tid;
            const int r = idx >> 3, s = idx & 7;
            const int ss = s ^ (r & 7);
            gl_lds16(Bb + (i64)r * ldbt + k0 + ss * 8, &Bsb[(t * 256 + w * 64) * 8]);
        }
        __syncthreads();

        #pragma unroll
        for (int ks = 0; ks < 2; ++ks) {
            const int slot = ks * 4 + kgrp;
            short8 a[4], b[4];
            #pragma unroll
            for (int i = 0; i < 4; ++i) {          // Bt rows (n side)
                const int r = wc * 64 + i * 16 + lr;
                a[i] = *(const short8*)&Bsb[r * 64 + ((slot ^ (r & 7)) << 3)];
            }
            #pragma unroll
            for (int j = 0; j < 4; ++j) {          // A rows (m side)
                const int r = wr * 64 + j * 16 + lr;
                b[j] = *(const short8*)&Asb[r * 64 + ((slot ^ (r & 7)) << 3)];
            }
            #pragma unroll
            for (int i = 0; i < 4; ++i)
                #pragma unroll
                for (int j = 0; j < 4; ++j)
                    acc[i][j] = __builtin_amdgcn_mfma_f32_16x16x32_bf16(
                        a[i], b[j], acc[i][j], 0, 0, 0);
        }
    }

    f32x4 bj[4];
    #pragma unroll
    for (int i = 0; i < 4; ++i) {
        const int nb = bnp + wc * 64 + i * 16 + kgrp * 4;
        bj[i] = bp ? *(const f32x4*)&bp[nb] : (f32x4){0.f, 0.f, 0.f, 0.f};
    }

    #pragma unroll
    for (int j = 0; j < 4; ++j) {
        const int m = bmp + wr * 64 + j * 16 + lr;
        #pragma unroll
        for (int i = 0; i < 4; ++i) {
            const int nb = bnp + wc * 64 + i * 16 + kgrp * 4;
            const i64 off = (i64)z * sC + (i64)m * ldc + nb;
            f32x4 v = acc[i][j] + bj[i];
            if (EPI == 0) {
                *(f32x4*)&((float*)Cv)[off] = v;
            } else if (EPI == 1) {
                ushort4 o;
                o.x = f2bf(v[0]); o.y = f2bf(v[1]);
                o.z = f2bf(v[2]); o.w = f2bf(v[3]);
                *(ushort4*)&((u16*)Cv)[off] = o;
            } else {
                u16* xp = (u16*)Cv + off;
                ushort4 old = *(const ushort4*)xp;
                ushort4 o;
                o.x = f2bf(bf2f(old.x) + fmaxf(v[0], 0.f));
                o.y = f2bf(bf2f(old.y) + fmaxf(v[1], 0.f));
                o.z = f2bf(bf2f(old.z) + fmaxf(v[2], 0.f));
                o.w = f2bf(bf2f(old.w) + fmaxf(v[3], 0.f));
                *(ushort4*)xp = o;
            }
        }
    }
}

// ---------------------------------------------------------------------------
// Fused 3-edge masked scores (MFMA) — round-4 config (empirical best 103us):
// 64x64 tile, 2-phase double-buffered staging, counted vmcnt(4), raw
// barriers, 32KB LDS, grid 8192 (b per XCD, h fastest, mt, nt).
// ---------------------------------------------------------------------------
__global__ __launch_bounds__(256) void scores_mfma(
    const u16* __restrict__ qb, const u16* __restrict__ kb,
    const int* __restrict__ adj, u16* __restrict__ sb)
{
    __shared__ u16 Qs[2][64 * 64];
    __shared__ u16 Ks[2][64 * 64];

    const int bid = blockIdx.x;
    const int b = bid & 7;
    const int t2 = bid >> 3;          // [0,1024)
    const int h = t2 & 3;
    const int mt = (t2 >> 2) & 15;
    const int nt = t2 >> 6;
    const int m0 = mt * 64, n0 = nt * 64;
    const int zga = h * 8 + b;

    const int tid = threadIdx.x;
    const int w = tid >> 6, l = tid & 63;
    const int wr = w >> 1, wc = w & 1;   // wr: n-half, wc: m-half
    const int kgrp = l >> 4, lr = l & 15;

    const i64 qoff = ((i64)b * Nv + n0) * Dv + h * DKv;
    const i64 koff = ((i64)b * Nv + m0) * Dv + h * DKv;

#define STAGE_SC(ci_, buf_) { \
    const int e_ = (ci_) / 3, k0_ = ((ci_) % 3) * 64; \
    const u16* qe_ = qb + (i64)e_ * BND + qoff; \
    const u16* ke_ = kb + (i64)e_ * BND + koff; \
    _Pragma("unroll") \
    for (int t = 0; t < 2; ++t) { \
        const int idx2 = t * 256 + tid; \
        const int r = idx2 >> 3, s = idx2 & 7; \
        const int ss = s ^ (r & 7); \
        gl_lds16(qe_ + (i64)r * Dv + k0_ + ss * 8, &Qs[buf_][(t * 256 + w * 64) * 8]); \
        gl_lds16(ke_ + (i64)r * Dv + k0_ + ss * 8, &Ks[buf_][(t * 256 + w * 64) * 8]); \
    } }

    int4 adjv[2][2];
    #pragma unroll
    for (int i = 0; i < 2; ++i) {
        const int mb = m0 + wc * 32 + i * 16 + kgrp * 4;
        #pragma unroll
        for (int j = 0; j < 2; ++j) {
            const int n = n0 + wr * 32 + j * 16 + lr;
            adjv[i][j] = *(const int4*)&adj[((i64)b * Nv + n) * Nv + mb];
        }
    }

    f32x4 acc[3][2][2];
    #pragma unroll
    for (int e = 0; e < 3; ++e)
        #pragma unroll
        for (int i = 0; i < 2; ++i)
            #pragma unroll
            for (int j = 0; j < 2; ++j)
                acc[e][i][j] = (f32x4){0.f, 0.f, 0.f, 0.f};

    STAGE_SC(0, 0)

    #pragma unroll
    for (int ci = 0; ci < 9; ++ci) {
        const int cur = ci & 1;
        if (ci < 8) {
            if (cur) { STAGE_SC(ci + 1, 0) } else { STAGE_SC(ci + 1, 1) }
            asm volatile("s_waitcnt vmcnt(4)" ::: "memory");
        } else {
            asm volatile("s_waitcnt vmcnt(0)" ::: "memory");
        }
        __builtin_amdgcn_s_barrier();
        asm volatile("" ::: "memory");

        const int e = ci / 3;
        #pragma unroll
        for (int ks = 0; ks < 2; ++ks) {
            const int slot = ks * 4 + kgrp;
            short8 a[2], bq2[2];
            #pragma unroll
            for (int i = 0; i < 2; ++i) {          // K rows (m side, reg dim)
                const int r = wc * 32 + i * 16 + lr;
                a[i] = *(const short8*)&Ks[cur][r * 64 + ((slot ^ (r & 7)) << 3)];
            }
            #pragma unroll
            for (int j = 0; j < 2; ++j) {          // Q rows (n side, lane dim)
                const int r = wr * 32 + j * 16 + lr;
                bq2[j] = *(const short8*)&Qs[cur][r * 64 + ((slot ^ (r & 7)) << 3)];
            }
            #pragma unroll
            for (int i = 0; i < 2; ++i)
                #pragma unroll
                for (int j = 0; j < 2; ++j)
                    acc[e][i][j] = __builtin_amdgcn_mfma_f32_16x16x32_bf16(
                        a[i], bq2[j], acc[e][i][j], 0, 0, 0);
        }

        asm volatile("s_waitcnt lgkmcnt(0)" ::: "memory");
        __builtin_amdgcn_s_barrier();
    }
#undef STAGE_SC

    const float scale = 0.07216878364870323f;  // 1/sqrt(192)
    #pragma unroll
    for (int i = 0; i < 2; ++i) {
        const int mb = m0 + wc * 32 + i * 16 + kgrp * 4;
        #pragma unroll
        for (int j = 0; j < 2; ++j) {
            const int n = n0 + wr * 32 + j * 16 + lr;
            const int av[4] = {adjv[i][j].x, adjv[i][j].y, adjv[i][j].z, adjv[i][j].w};
            ushort4 o;
            #pragma unroll
            for (int rg = 0; rg < 4; ++rg) {
                float f = 0.f;
                if (av[rg] == 1) f = acc[0][i][j][rg];
                else if (av[rg] == 2) f = acc[1][i][j][rg];
                else if (av[rg] == 3) f = acc[2][i][j][rg];
                f *= scale;
                if (f == 0.f) f = -1e9f;
                ((u16*)&o)[rg] = f2bf(f);
            }
            *(ushort4*)&sb[((i64)zga * Nv + n) * Nv + mb] = o;
        }
    }
}

// row softmax over 1024 cols: read S bf16, write ga f32 (output) + P bf16
__global__ __launch_bounds__(256) void softmax_k(const u16* __restrict__ sb,
                                                 float* __restrict__ ga,
                                                 u16* __restrict__ gab)
{
    const i64 row = blockIdx.x;
    const int tid = threadIdx.x;
    const int wid = tid >> 6, lane = tid & 63;

    ushort4 sv = *(const ushort4*)&sb[row * (i64)Nv + tid * 4];
    float4 v;
    v.x = bf2f(sv.x); v.y = bf2f(sv.y); v.z = bf2f(sv.z); v.w = bf2f(sv.w);

    float m = fmaxf(fmaxf(v.x, v.y), fmaxf(v.z, v.w));
    #pragma unroll
    for (int o = 32; o >= 1; o >>= 1) m = fmaxf(m, __shfl_xor(m, o));

    __shared__ float red[4];
    if (lane == 0) red[wid] = m;
    __syncthreads();
    m = fmaxf(fmaxf(red[0], red[1]), fmaxf(red[2], red[3]));

    float e0 = expf(v.x - m), e1 = expf(v.y - m), e2 = expf(v.z - m), e3 = expf(v.w - m);
    float s = e0 + e1 + e2 + e3;
    #pragma unroll
    for (int o = 32; o >= 1; o >>= 1) s += __shfl_xor(s, o);
    __syncthreads();
    if (lane == 0) red[wid] = s;
    __syncthreads();
    s = red[0] + red[1] + red[2] + red[3];

    const float inv = 1.0f / s;
    float4 o;
    o.x = e0 * inv; o.y = e1 * inv; o.z = e2 * inv; o.w = e3 * inv;
    *(float4*)&ga[row * (i64)Nv + tid * 4] = o;

    ushort4 ob;
    ob.x = f2bf(o.x); ob.y = f2bf(o.y); ob.z = f2bf(o.z); ob.w = f2bf(o.w);
    *(ushort4*)&gab[row * (i64)Nv + tid * 4] = ob;
}

// nodes f32 -> nodesb bf16 + X broadcast x4 (one read, five writes)
__global__ __launch_bounds__(256) void prep_k(const float* __restrict__ nodes,
                                              u16* __restrict__ nodesb,
                                              u16* __restrict__ Xb)
{
    const i64 i = (i64)blockIdx.x * 256 + threadIdx.x;  // over BND/4
    float4 v = ((const float4*)nodes)[i];
    ushort4 o;
    o.x = f2bf(v.x); o.y = f2bf(v.y); o.z = f2bf(v.z); o.w = f2bf(v.w);
    ((ushort4*)nodesb)[i] = o;
    const i64 q4 = BND / 4;
    #pragma unroll
    for (int h = 0; h < Hh; ++h) ((ushort4*)Xb)[(i64)h * q4 + i] = o;
}

// all weight transposes in one dispatch. z<3: Wq[e]; 3..5: Wk[e]; 6,7: gcnW;
// 8..11: Wagg 768-row slice. All 768x768 transposes.
__global__ __launch_bounds__(256) void trans_all(
    const float* __restrict__ Wq, const float* __restrict__ Wk,
    const float* __restrict__ gcnW, const float* __restrict__ Wagg,
    u16* __restrict__ wqkt, u16* __restrict__ gcnWt, u16* __restrict__ waggt)
{
    const int z = blockIdx.z;
    const i64 W768 = (i64)768 * 768;
    const float* src;
    u16* dst;
    int ldo;
    if (z < 3)      { src = Wq + z * W768;        dst = wqkt + z * W768;          ldo = 768; }
    else if (z < 6) { src = Wk + (z - 3) * W768;  dst = wqkt + (i64)z * W768;     ldo = 768; }
    else if (z < 8) { src = gcnW + (z - 6) * W768; dst = gcnWt + (i64)(z - 6) * W768; ldo = 768; }
    else            { src = Wagg + (i64)(z - 8) * W768; dst = waggt + (i64)(z - 8) * 768; ldo = 3072; }

    __shared__ u16 t[32][33];
    const int c0 = blockIdx.x * 32, r0 = blockIdx.y * 32;
    const int tx = threadIdx.x & 31, ty = threadIdx.x >> 5;
    #pragma unroll
    for (int i = ty; i < 32; i += 8)
        t[i][tx] = f2bf(src[(i64)(r0 + i) * 768 + c0 + tx]);
    __syncthreads();
    #pragma unroll
    for (int i = ty; i < 32; i += 8)
        dst[(i64)(c0 + i) * ldo + r0 + tx] = t[tx][i];
}

// out = p0 + p1 + bias (split-K reduce), float4 per thread
__global__ __launch_bounds__(256) void addbias_k(
    const float* __restrict__ p0, const float* __restrict__ p1,
    const float* __restrict__ bias, float* __restrict__ out)
{
    const i64 i4 = (i64)blockIdx.x * 256 + threadIdx.x;  // over BND/4
    const int nb = (int)((i4 * 4) % Dv);
    float4 a = ((const float4*)p0)[i4];
    float4 b = ((const float4*)p1)[i4];
    float4 bv = *(const float4*)&bias[nb];
    float4 o;
    o.x = a.x + b.x + bv.x; o.y = a.y + b.y + bv.y;
    o.z = a.z + b.z + bv.z; o.w = a.w + b.w + bv.w;
    ((float4*)out)[i4] = o;
}

// ---------------------------------------------------------------------------
extern "C" void kernel_launch(void* const* d_in, const int* in_sizes, int n_in,
                              void* d_out, int out_size, void* d_ws, size_t ws_size,
                              hipStream_t stream)
{
    const float* nodes = (const float*)d_in[0];
    const int*   adj   = (const int*)d_in[1];
    const float* Wq    = (const float*)d_in[2];
    const float* bq    = (const float*)d_in[3];
    const float* Wk    = (const float*)d_in[4];
    const float* bk    = (const float*)d_in[5];
    const float* gcnW  = (const float*)d_in[6];
    const float* gcnb  = (const float*)d_in[7];
    const float* Wagg  = (const float*)d_in[8];
    const float* bagg  = (const float*)d_in[9];

    float* out = (float*)d_out;             // (B,N,D) f32
    float* gaf = out + BND;                 // (H,B,N,N) f32

    const i64 W768 = (i64)768 * 768;
    const i64 HTZ  = (i64)768 * 1024;       // per-z H^T slab (d-major, 1024 cols)
    u16* ws     = (u16*)d_ws;
    u16* qb     = ws;                       // 3*BND           (phase 1)
    u16* kb2    = ws + 3 * BND;             // 3*BND           (phase 1)
    u16* gab    = ws;                       // HBND bf16       (alias after scores)
    u16* nodesb = ws + 6 * BND;             // BND
    u16* gcnWt  = nodesb + BND;             // 2*W768
    u16* waggt  = gcnWt + 2 * W768;         // 4*W768
    u16* Xb     = waggt + 4 * W768;         // HBND
    u16* Htz    = Xb + HBND;                // 32*HTZ == HBND, time-shared:
    u16* wqkt   = Htz;                      //   6*W768 (dead after q/k proj)
    u16* sbuf   = Htz;                      //   HBND (S bf16; dead after softmax)
    float* part = (float*)Htz;              //   2*BND f32 (final split-K)

    dim3 blk(256);

    prep_k<<<dim3((unsigned)(BND / 4 / 256)), blk, 0, stream>>>(nodes, nodesb, Xb);
    trans_all<<<dim3(24, 24, 12), blk, 0, stream>>>(Wq, Wk, gcnW, Wagg, wqkt, gcnWt, waggt);

    // fused q/k projections: z 0..2 -> q (bias bq), z 3..5 -> k (bias bk)
    gemm_bf16<1, false, 1, 6, 64, 6><<<dim3(2304), blk, 0, stream>>>(
        nodesb, 0, Dv, wqkt, W768, Dv, -1, bq, Dv, bk, qb, BND, Dv, Dv, 0);

    // fused masked scores -> S bf16 scratch (round-4 config)
    scores_mfma<<<dim3(8192), blk, 0, stream>>>(qb, kb2, adj, sbuf);

    // softmax: ga f32 (output) + P bf16 (gab aliases q/k, both dead now)
    softmax_k<<<dim3(Hh * Bv * Nv), blk, 0, stream>>>(sbuf, gaf, gab);

    for (int it = 0; it < 2; ++it) {
        if (it == 0) {
            // iter 0: X identical across heads -> per-b H0^T = gcnW[0]^T @ nodes[b]^T
            // Htz[b] is [768][1024] contiguous; Xupd indexes it by z&7.
            gemm_bf16<1, false, 0, 8, 6, 8><<<dim3(384), blk, 0, stream>>>(
                gcnWt, 0, Dv, nodesb, (i64)Nv * Dv, Dv, 7, nullptr, 0, nullptr,
                Htz, HTZ, 1024, Dv, 0);
            gemm_bf16<2, false, 0, 6, 8, 32><<<dim3(1536), blk, 0, stream>>>(
                gab, (i64)Nv * Nv, Nv, Htz, HTZ, 1024, 7, gcnb, 0, nullptr,
                Xb, (i64)Nv * Dv, Dv, Nv, 0);
        } else {
            // iter 1: per-z H^T = gcnW[1]^T @ X[z]^T, Htz[z] = [768][1024]
            gemm_bf16<1, false, 0, 8, 6, 32><<<dim3(1536), blk, 0, stream>>>(
                gcnWt + W768, 0, Dv, Xb, (i64)Nv * Dv, Dv, 31, nullptr, 0, nullptr,
                Htz, HTZ, 1024, Dv, 0);
            gemm_bf16<2, false, 0, 6, 8, 32><<<dim3(1536), blk, 0, stream>>>(
                gab, (i64)Nv * Nv, Nv, Htz, HTZ, 1024, 31, gcnb + (i64)Dv, 0, nullptr,
                Xb, (i64)Nv * Dv, Dv, Nv, 0);
        }
    }

    // final: out = cat(X) @ W_agg + b_agg, split-K x2 into f32 partials
    gemm_bf16<0, true, 0, 6, 64, 2><<<dim3(768), blk, 0, stream>>>(
        Xb, 0, Dv, waggt, 0, Hh * Dv, -1, nullptr, 0, nullptr,
        part, BND, Dv, (Hh * Dv) / 2, (Hh * Dv) / 2);

    addbias_k<<<dim3((unsigned)(BND / 4 / 256)), blk, 0, stream>>>(
        part, part + BND, bagg, out);
}